// Round 8
// baseline (310.199 us; speedup 1.0000x reference)
//
#include <hip/hip_runtime.h>
#include <stdint.h>
#include <stddef.h>

// ThresholdMoE: out = sum_e w[n,e] * (x @ A_e) @ B_e, w = renorm(softmax(x@gw+b) >= 0.1)
// N=65536 tokens, D=1024, E=8, R=64, ER=512.
// R8: R7 fusion with LDS strides reverted to 16B-aligned 40/520 (R7's 42/522
//     broke ds_read_b128/uint2 alignment => garbage). Gate: upfront-16-load.

typedef float f32x4 __attribute__((ext_vector_type(4)));
typedef short bf16x8 __attribute__((ext_vector_type(8)));

#define MFMA_16x16x32(A, B, C) __builtin_amdgcn_mfma_f32_16x16x32_bf16((A), (B), (C), 0, 0, 0)
#define SCHED_FENCE() __builtin_amdgcn_sched_barrier(0)
#define BAR() __builtin_amdgcn_s_barrier()
#define WAIT_LGKM0() asm volatile("s_waitcnt lgkmcnt(0)" ::: "memory")
#define WAIT_VM0_LGKM0() asm volatile("s_waitcnt vmcnt(0) lgkmcnt(0)" ::: "memory")

__device__ __forceinline__ unsigned short f2bf(float f) {
    union { float f; unsigned int u; } v;
    v.f = f;
    unsigned int u = v.u;
    u += 0x7FFFu + ((u >> 16) & 1u);   // RNE
    return (unsigned short)(u >> 16);
}

__device__ __forceinline__ void load16_lds(unsigned short* lds, const unsigned short* g) {
    __builtin_amdgcn_global_load_lds(
        (const __attribute__((address_space(1))) unsigned int*)g,
        (__attribute__((address_space(3))) unsigned int*)lds, 16, 0, 0);
}

// ---------------------------------------------------------------------------
// Pack lora_A / lora_B to bf16 in MFMA B-fragment order.
// A_P: [D/32=32][ER/16=32][lane 64][j 8], element = A_cat[d][e*64+r]
// B_P: [ER/32=16][D/16=64][lane 64][j 8], element = B_cat[e*64+r][d]
// ---------------------------------------------------------------------------
__global__ __launch_bounds__(256) void convert_pack(
        const float* __restrict__ LA, const float* __restrict__ LB,
        unsigned short* __restrict__ A_P, unsigned short* __restrict__ B_P) {
    int gid = blockIdx.x * 256 + threadIdx.x;          // 0 .. 1048575
    if (gid < 524288) {
        int j = gid & 7, l = (gid >> 3) & 63, cblk = (gid >> 9) & 31, kblk = gid >> 14;
        int d = kblk * 32 + (l >> 4) * 8 + j;
        int col = cblk * 16 + (l & 15);
        int e = col >> 6, r = col & 63;
        A_P[gid] = f2bf(LA[((size_t)e * 1024 + d) * 64 + r]);   // lora_A[e][d][r]
    } else {
        int idx = gid - 524288;
        int j = idx & 7, l = (idx >> 3) & 63, cblk = (idx >> 9) & 63, kblk = idx >> 15;
        int k = kblk * 32 + (l >> 4) * 8 + j;          // index into ER
        int d = cblk * 16 + (l & 15);
        int e = k >> 6, r = k & 63;
        B_P[idx] = f2bf(LB[((size_t)e * 64 + r) * 1024 + d]);   // lora_B[e][r][d]
    }
}

// ---------------------------------------------------------------------------
// Gate: fp32, exact. 16 threads/token (row=tid>>4, sub=tid&15). GW transposed
// in LDS. ALL 16 X loads issued upfront into registers (max memory-level
// parallelism), then consumed per-it with g[8] register-cached from LDS.
// Per-accumulator FMA order + reduce tree bit-identical to R4/R6.
// ---------------------------------------------------------------------------
__global__ __launch_bounds__(256) void gate_kernel(
        const float* __restrict__ X, const float* __restrict__ GW,
        const float* __restrict__ GB, float* __restrict__ Wg) {
    __shared__ float gwt[8 * 1024];   // 32KB: GW_T[e][k]
    int tid = threadIdx.x;

    {   // stage GW transposed: thread t loads GW rows [t*4, t*4+4)
        float r[4][8];
#pragma unroll
        for (int j = 0; j < 4; ++j) {
            const f32x4* gp = (const f32x4*)(GW + (size_t)(tid * 4 + j) * 8);
            f32x4 g0 = gp[0], g1 = gp[1];
#pragma unroll
            for (int q = 0; q < 4; ++q) { r[j][q] = g0[q]; r[j][4 + q] = g1[q]; }
        }
#pragma unroll
        for (int e = 0; e < 8; ++e) {
            f32x4 v;
#pragma unroll
            for (int j = 0; j < 4; ++j) v[j] = r[j][e];
            *(f32x4*)&gwt[e * 1024 + tid * 4] = v;
        }
    }
    __syncthreads();

    int row = blockIdx.x * 16 + (tid >> 4);
    int sub = tid & 15;
    const float* xr = X + (size_t)row * 1024 + sub * 4;

    // issue ALL X loads upfront — 16 wave-loads in flight per wave
    f32x4 xs[16];
#pragma unroll
    for (int it = 0; it < 16; ++it) xs[it] = *(const f32x4*)(xr + it * 64);

    float lg[8];
#pragma unroll
    for (int e = 0; e < 8; ++e) lg[e] = 0.f;

#pragma unroll
    for (int it = 0; it < 16; ++it) {
        f32x4 g[8];
#pragma unroll
        for (int e = 0; e < 8; ++e)
            g[e] = *(const f32x4*)&gwt[e * 1024 + it * 64 + sub * 4];
        f32x4 x = xs[it];
#pragma unroll
        for (int e = 0; e < 8; ++e) {
            lg[e] += x[0] * g[e][0];
            lg[e] += x[1] * g[e][1];
            lg[e] += x[2] * g[e][2];
            lg[e] += x[3] * g[e][3];
        }
    }
#pragma unroll
    for (int s = 1; s < 16; s <<= 1) {
#pragma unroll
        for (int e = 0; e < 8; ++e) lg[e] += __shfl_xor(lg[e], s, 16);
    }
    float p[8], m = -1e30f, ssum = 0.f;
#pragma unroll
    for (int e = 0; e < 8; ++e) { lg[e] += GB[e]; m = fmaxf(m, lg[e]); }
#pragma unroll
    for (int e = 0; e < 8; ++e) { p[e] = expf(lg[e] - m); ssum += p[e]; }
    float inv = 1.f / ssum;
    float wv[8], wsum = 0.f;
#pragma unroll
    for (int e = 0; e < 8; ++e) {
        float pe = p[e] * inv;
        wv[e] = (pe >= 0.1f) ? pe : 0.f;
        wsum += wv[e];
    }
    if (wsum == 0.f) wsum = 1.f;
    float invw = 1.f / wsum;
    if (sub < 8) Wg[(size_t)row * 8 + sub] = wv[sub] * invw;
}

// ---------------------------------------------------------------------------
// Fused stages: per 64-token block, 8 waves.
// Phase 1 (R4-validated stage1): H = w * (x @ A_cat) -> LDS hb[64][520].
// Phase 2: out[64][1024] = hb @ B_cat; A-frags read from hb (stride 520:
// 16B-aligned, 2-way banks = free), B-frags global->reg (B_P L2-resident).
// H never touches HBM.
// ---------------------------------------------------------------------------
__global__ __launch_bounds__(512, 4) void fused_kernel(
        const float* __restrict__ X, const unsigned short* __restrict__ A_P,
        const unsigned short* __restrict__ B_P, const float* __restrict__ Wg,
        float* __restrict__ Out) {
    __shared__ union SM1 {
        struct {
            unsigned short a[2][32 * 512];   // 2 x 32KB packed-A tiles
            unsigned short x[2][64 * 40];    // 2 x 5KB bf16 X ([64][32+8pad])
        } p;
        unsigned short hb[64 * 520];         // H tile [64][512+8 pad], 66560B
    } sm;
    __shared__ float wl[512];                // weights [64 tok][8 e]

    int tid = threadIdx.x;
    int lane = tid & 63;
    int w = tid >> 6;                        // wave 0..7 == expert id (phase 1)
    int blk = blockIdx.x;
    int row = tid >> 3;                      // 0..63 (X staging row)
    int sub = tid & 7;

    wl[tid] = Wg[(size_t)blk * 512 + tid];

    const float* xp = X + (size_t)blk * 64 * 1024 + (size_t)row * 1024 + sub * 4;
    unsigned short* aCur = sm.p.a[0];
    unsigned short* aNxt = sm.p.a[1];
    unsigned short* xCur = sm.p.x[0];
    unsigned short* xNxt = sm.p.x[1];

    // ---- phase 1 prologue ----
    {
        const unsigned short* asrc = A_P + tid * 8;
#pragma unroll
        for (int i = 0; i < 4; ++i)
            load16_lds(&aCur[tid * 8 + i * 4096], asrc + i * 4096);
    }
    SCHED_FENCE();
    f32x4 xv0 = *(const f32x4*)(xp);
    f32x4 xv_hold = *(const f32x4*)(xp + 32);
    {   // write x(0); implicit wait for xv0 also drains GLL A(0)
        unsigned int lo = (unsigned int)f2bf(xv0[0]) | ((unsigned int)f2bf(xv0[1]) << 16);
        unsigned int hi = (unsigned int)f2bf(xv0[2]) | ((unsigned int)f2bf(xv0[3]) << 16);
        *((uint2*)&xCur[row * 40 + sub * 4]) = make_uint2(lo, hi);
    }

    f32x4 acc[4][4] = {};
    for (int kb = 0; kb < 31; ++kb) {
        const unsigned short* asrc = A_P + (size_t)(kb + 1) * 16384 + tid * 8;
#pragma unroll
        for (int i = 0; i < 4; ++i)
            load16_lds(&aNxt[tid * 8 + i * 4096], asrc + i * 4096);
        SCHED_FENCE();
        int kbn = (kb + 2 <= 31) ? kb + 2 : 31;
        f32x4 xv_new = *(const f32x4*)(xp + (size_t)kbn * 32);
        // write x(kb+1); implicit vmcnt wait on xv_hold drains GLL A(kb)
        unsigned int lo = (unsigned int)f2bf(xv_hold[0]) | ((unsigned int)f2bf(xv_hold[1]) << 16);
        unsigned int hi = (unsigned int)f2bf(xv_hold[2]) | ((unsigned int)f2bf(xv_hold[3]) << 16);
        *((uint2*)&xNxt[row * 40 + sub * 4]) = make_uint2(lo, hi);
        WAIT_LGKM0();
        SCHED_FENCE();
        BAR();
        SCHED_FENCE();
        bf16x8 af[4], bv[4];
#pragma unroll
        for (int m = 0; m < 4; ++m)
            af[m] = *(const bf16x8*)&xCur[(m * 16 + (lane & 15)) * 40 + (lane >> 4) * 8];
#pragma unroll
        for (int n = 0; n < 4; ++n)
            bv[n] = *(const bf16x8*)&aCur[(w * 4 + n) * 512 + lane * 8];
#pragma unroll
        for (int m = 0; m < 4; ++m)
#pragma unroll
            for (int n = 0; n < 4; ++n)
                acc[m][n] = MFMA_16x16x32(af[m], bv[n], acc[m][n]);
        BAR();
        unsigned short* t;
        t = aCur; aCur = aNxt; aNxt = t;
        t = xCur; xCur = xNxt; xNxt = t;
        xv_hold = xv_new;
    }
    // peeled kb=31
    WAIT_VM0_LGKM0();
    SCHED_FENCE();
    BAR();
    SCHED_FENCE();
    {
        bf16x8 af[4], bv[4];
#pragma unroll
        for (int m = 0; m < 4; ++m)
            af[m] = *(const bf16x8*)&xCur[(m * 16 + (lane & 15)) * 40 + (lane >> 4) * 8];
#pragma unroll
        for (int n = 0; n < 4; ++n)
            bv[n] = *(const bf16x8*)&aCur[(w * 4 + n) * 512 + lane * 8];
#pragma unroll
        for (int m = 0; m < 4; ++m)
#pragma unroll
            for (int n = 0; n < 4; ++n)
                acc[m][n] = MFMA_16x16x32(af[m], bv[n], acc[m][n]);
    }
    __syncthreads();   // staging dead; hb (union) becomes live

    // phase 1 epilogue: scale by weight, bf16 -> hb[64][520]
#pragma unroll
    for (int m = 0; m < 4; ++m) {
        float wv[4];
#pragma unroll
        for (int r = 0; r < 4; ++r)
            wv[r] = wl[(m * 16 + (lane >> 4) * 4 + r) * 8 + w];
#pragma unroll
        for (int n = 0; n < 4; ++n) {
            int col = w * 64 + n * 16 + (lane & 15);
#pragma unroll
            for (int r = 0; r < 4; ++r) {
                int rr = m * 16 + (lane >> 4) * 4 + r;
                sm.hb[rr * 520 + col] = f2bf(acc[m][n][r] * wv[r]);
            }
        }
    }
    __syncthreads();

    // ---- phase 2: out = hb @ B_cat (wave w owns cols w*128..+127) ----
#pragma unroll
    for (int h = 0; h < 2; ++h) {
        f32x4 acc2[4][4] = {};
        int cb0 = w * 8 + h * 4;             // cblk base (16-col blocks)
        for (int kc = 0; kc < 16; ++kc) {
            bf16x8 af2[4], bv2[4];
#pragma unroll
            for (int n = 0; n < 4; ++n)
                bv2[n] = *(const bf16x8*)(B_P + (((size_t)kc * 64 + cb0 + n) * 64 + lane) * 8);
#pragma unroll
            for (int m = 0; m < 4; ++m)
                af2[m] = *(const bf16x8*)&sm.hb[(m * 16 + (lane & 15)) * 520 + kc * 32 + (lane >> 4) * 8];
#pragma unroll
            for (int m = 0; m < 4; ++m)
#pragma unroll
                for (int n = 0; n < 4; ++n)
                    acc2[m][n] = MFMA_16x16x32(af2[m], bv2[n], acc2[m][n]);
        }
        size_t rb = (size_t)blk * 64;
        int cb = w * 128 + h * 64;
#pragma unroll
        for (int m = 0; m < 4; ++m)
#pragma unroll
            for (int n = 0; n < 4; ++n) {
                int col = cb + n * 16 + (lane & 15);
#pragma unroll
                for (int r = 0; r < 4; ++r) {
                    size_t rrow = rb + m * 16 + (lane >> 4) * 4 + r;
                    Out[rrow * 1024 + col] = acc2[m][n][r];
                }
            }
    }
}

// ---------------------------------------------------------------------------
extern "C" void kernel_launch(void* const* d_in, const int* in_sizes, int n_in,
                              void* d_out, int out_size, void* d_ws, size_t ws_size,
                              hipStream_t stream) {
    const float* X  = (const float*)d_in[0];   // [65536][1024]
    const float* GW = (const float*)d_in[1];   // [1024][8]
    const float* GB = (const float*)d_in[2];   // [8]
    const float* LA = (const float*)d_in[3];   // [8][1024][64]
    const float* LB = (const float*)d_in[4];   // [8][64][1024]
    float* Out = (float*)d_out;                // [65536][1024]

    char* ws = (char*)d_ws;
    float*          Wg  = (float*)ws;                              // 2MB  [N][8]
    unsigned short* A_P = (unsigned short*)(ws + (2u << 20));      // 1MB  packed lora_A
    unsigned short* B_P = (unsigned short*)(ws + (3u << 20));      // 1MB  packed lora_B

    convert_pack<<<4096, 256, 0, stream>>>(LA, LB, A_P, B_P);
    gate_kernel<<<4096, 256, 0, stream>>>(X, GW, GB, Wg);
    fused_kernel<<<1024, 512, 0, stream>>>(X, A_P, B_P, Wg, Out);
}